// Round 7
// baseline (217.784 us; speedup 1.0000x reference)
//
#include <hip/hip_runtime.h>
#include <hip/hip_bf16.h>
#include <stdint.h>

#define NP 30000
#define BBINS 80
#define INCH 16
#define OUTCH 32
#define KDIM 1280       // BBINS*INCH
#define NDIM 512        // OUTCH*TBINS
#define KSTEPS 40       // KDIM/32  (BK=32 = 2 bins)
#define MTILES 469      // ceil(NP/64)

typedef __bf16 bf16x8 __attribute__((ext_vector_type(8)));
typedef float f32x4 __attribute__((ext_vector_type(4)));

__device__ __forceinline__ void async_ld16(const void* g, void* l) {
    __builtin_amdgcn_global_load_lds(
        (const __attribute__((address_space(1))) unsigned int*)g,
        (__attribute__((address_space(3))) unsigned int*)l,
        16, 0, 0);
}

// ---------------------------------------------------------------------------
// Prep: PW[kc][n][qs][e] bf16 with chunk-XOR swizzle qs ^ ((n>>1)&3), where
// lw[k][n] = W[(b+5t)%80][c][o], k=b*16+c, n=o*16+t. (unchanged, proven)
// ---------------------------------------------------------------------------
__global__ void prep_weights(const float* __restrict__ w, __bf16* __restrict__ pw) {
    int gid = blockIdx.x * 256 + threadIdx.x;           // 655360 total
    int e  = gid & 7;
    int qs = (gid >> 3) & 3;
    int n  = (gid >> 5) & 511;
    int kc = gid >> 14;                                  // 0..39
    int kp = kc * 32 + ((qs ^ ((n >> 1) & 3)) << 3) + e; // 0..1279
    int b = kp >> 4, c = kp & 15;
    int o = n >> 4,  t = n & 15;
    int bid = (b + 5 * t) % BBINS;
    pw[gid] = (__bf16)w[(bid * INCH + c) * OUTCH + o];
}

// ---------------------------------------------------------------------------
// FUSED gather + GEMM + max-over-t, with SOFTWARE-PIPELINED gather (T14).
// R6 diagnosis: fusion removed the 150MB h round-trip (FETCH 78->50MB) but
// time was flat at ~115us because the gather's L2 latency moved INSIDE the
// barrier-locked k-step: chain = x-load(~300-600cy) -> FMA -> ds_write ->
// barrier -> MFMA(160cy) -> barrier, ~3770cy/kstep, everything idle
// (MfmaUtil 13%, BW 6%).
// Fix: x-values held ONE k-step ahead, metadata TWO k-steps ahead, in regs:
//   step kc: [B async issue] [hv = VALU on preloaded x(kc); ds_write]
//            [issue x(kc+1) via preloaded meta(kc+1)] [issue meta(kc+2), NT]
//            [sync] [ds_read + 32 MFMA] [sync]
// The gather loads get ~2 k-steps of slack instead of sitting on the
// critical path; only the B-drain at the barrier stays exposed.
// Everything else verbatim-proven (R6 refcheck): B via global_load_lds from
// pre-swizzled pw, chunk-XOR write swizzle on A ds_write matching the
// q^((row>>1)&3) read swizzle, 4x8 acc wave tile, shfl-max epilogue.
// ---------------------------------------------------------------------------
__global__ __launch_bounds__(256, 2) void fused_gemm_max(
    const float* __restrict__ x,
    const int*   __restrict__ cidx,
    const float* __restrict__ cval,
    const __bf16* __restrict__ pw,
    float* __restrict__ out) {

    __shared__ __align__(16) __bf16 Alds[64 * 32];       // 4 KB
    __shared__ __align__(16) __bf16 Blds[512 * 32];      // 32 KB

    const int mbase = blockIdx.x * 64;
    const int tid  = threadIdx.x;
    const int lane = tid & 63;
    const int wave = tid >> 6;           // n-col group 0..3

    // ---- gather unit mapping ----
    const int patch_l = tid >> 2;        // 0..63
    const int chunk   = tid & 3;         // k-chunk within 64B row
    const int bin_l   = chunk >> 1;      // 0..1
    const int half    = chunk & 1;       // 8-ch half
    int p = mbase + patch_l;
    if (p > NP - 1) p = NP - 1;          // clamp tail (out-write guarded)
    const int row0 = p * BBINS + bin_l;  // conn row; +2 per kstep
    char* aW = (char*)Alds + patch_l * 64
             + ((chunk ^ ((patch_l >> 1) & 3)) << 4);   // swizzled write slot

    // ---- MFMA read offsets (proven swizzle) ----
    const int ml = lane & 15, q = lane >> 4;
    const int f = (ml >> 1) & 3;
    int a_off[4], b_off[8];
#pragma unroll
    for (int i = 0; i < 4; ++i)
        a_off[i] = (i * 16 + ml) * 64 + ((q ^ f) << 4);
#pragma unroll
    for (int j = 0; j < 8; ++j) {
        int nl = wave * 128 + j * 16 + ml;
        b_off[j] = nl * 64 + ((q ^ f) << 4);
    }

    f32x4 acc[4][8];
#pragma unroll
    for (int i = 0; i < 4; ++i)
#pragma unroll
        for (int j = 0; j < 8; ++j)
            acc[i][j] = (f32x4){0.f, 0.f, 0.f, 0.f};

    const char* pwB = (const char*)pw + tid * 16;
    char* bDst = (char*)Blds + tid * 16;

    // ---- gather pipeline prologue ----
    // meta(0) -> va/ia; x(0) -> xa; meta(1) -> vb/ib
    int r3 = row0 * 3;
    int   ia0 = cidx[r3], ia1 = cidx[r3 + 1], ia2 = cidx[r3 + 2];
    float va0 = cval[r3], va1 = cval[r3 + 1], va2 = cval[r3 + 2];
    const float* xp;
    xp = x + (size_t)(unsigned)ia0 * 16 + half * 8;
    float4 xa0 = *(const float4*)xp, xa1 = *(const float4*)(xp + 4);
    xp = x + (size_t)(unsigned)ia1 * 16 + half * 8;
    float4 xa2 = *(const float4*)xp, xa3 = *(const float4*)(xp + 4);
    xp = x + (size_t)(unsigned)ia2 * 16 + half * 8;
    float4 xa4 = *(const float4*)xp, xa5 = *(const float4*)(xp + 4);
    r3 = (row0 + 2) * 3;
    int   ib0 = cidx[r3], ib1 = cidx[r3 + 1], ib2 = cidx[r3 + 2];
    float vb0 = cval[r3], vb1 = cval[r3 + 1], vb2 = cval[r3 + 2];

    for (int kc = 0; kc < KSTEPS; ++kc) {
        // B: 32KB k-chunk, 8 x async 4KB (linear dest, swizzle baked in pw)
        const char* bs = pwB + kc * 32768;
#pragma unroll
        for (int i = 0; i < 8; ++i)
            async_ld16(bs + i * 4096, bDst + i * 4096);

        // A: pure-VALU combine of preloaded x(kc), then ds_write
        bf16x8 hv;
        hv[0] = (__bf16)(va0 * xa0.x + va1 * xa2.x + va2 * xa4.x);
        hv[1] = (__bf16)(va0 * xa0.y + va1 * xa2.y + va2 * xa4.y);
        hv[2] = (__bf16)(va0 * xa0.z + va1 * xa2.z + va2 * xa4.z);
        hv[3] = (__bf16)(va0 * xa0.w + va1 * xa2.w + va2 * xa4.w);
        hv[4] = (__bf16)(va0 * xa1.x + va1 * xa3.x + va2 * xa5.x);
        hv[5] = (__bf16)(va0 * xa1.y + va1 * xa3.y + va2 * xa5.y);
        hv[6] = (__bf16)(va0 * xa1.z + va1 * xa3.z + va2 * xa5.z);
        hv[7] = (__bf16)(va0 * xa1.w + va1 * xa3.w + va2 * xa5.w);
        *(bf16x8*)aW = hv;                               // ds_write_b128

        // prefetch x(kc+1) via meta(kc+1); latency hides under 2 barriers
        float4 nx0 = xa0, nx1 = xa1, nx2 = xa2, nx3 = xa3, nx4 = xa4, nx5 = xa5;
        if (kc + 1 < KSTEPS) {
            xp = x + (size_t)(unsigned)ib0 * 16 + half * 8;
            nx0 = *(const float4*)xp; nx1 = *(const float4*)(xp + 4);
            xp = x + (size_t)(unsigned)ib1 * 16 + half * 8;
            nx2 = *(const float4*)xp; nx3 = *(const float4*)(xp + 4);
            xp = x + (size_t)(unsigned)ib2 * 16 + half * 8;
            nx4 = *(const float4*)xp; nx5 = *(const float4*)(xp + 4);
        }
        // prefetch meta(kc+2), nontemporal (streamed once; keep x/pw in L2)
        int   ni0 = ib0, ni1 = ib1, ni2 = ib2;
        float nv0 = vb0, nv1 = vb1, nv2 = vb2;
        if (kc + 2 < KSTEPS) {
            r3 = (row0 + (kc + 2) * 2) * 3;
            ni0 = __builtin_nontemporal_load(cidx + r3 + 0);
            ni1 = __builtin_nontemporal_load(cidx + r3 + 1);
            ni2 = __builtin_nontemporal_load(cidx + r3 + 2);
            nv0 = __builtin_nontemporal_load(cval + r3 + 0);
            nv1 = __builtin_nontemporal_load(cval + r3 + 1);
            nv2 = __builtin_nontemporal_load(cval + r3 + 2);
        }
        __syncthreads();                                 // drains vm+lgkm

        bf16x8 af[4], bfr[8];
#pragma unroll
        for (int i = 0; i < 4; ++i)
            af[i] = *(const bf16x8*)((const char*)Alds + a_off[i]);
#pragma unroll
        for (int j = 0; j < 8; ++j)
            bfr[j] = *(const bf16x8*)((const char*)Blds + b_off[j]);
#pragma unroll
        for (int i = 0; i < 4; ++i)
#pragma unroll
            for (int j = 0; j < 8; ++j)
                acc[i][j] = __builtin_amdgcn_mfma_f32_16x16x32_bf16(
                    af[i], bfr[j], acc[i][j], 0, 0, 0);
        __syncthreads();

        // rotate pipeline registers
        va0 = vb0; va1 = vb1; va2 = vb2;
        xa0 = nx0; xa1 = nx1; xa2 = nx2; xa3 = nx3; xa4 = nx4; xa5 = nx5;
        ib0 = ni0; ib1 = ni1; ib2 = ni2;
        vb0 = nv0; vb1 = nv1; vb2 = nv2;
    }

    const int rgrp = lane >> 4;
    const int tl   = lane & 15;
#pragma unroll
    for (int i = 0; i < 4; ++i) {
#pragma unroll
        for (int j = 0; j < 8; ++j) {
            float v0r = acc[i][j][0], v1r = acc[i][j][1];
            float v2r = acc[i][j][2], v3r = acc[i][j][3];
#pragma unroll
            for (int off = 1; off < 16; off <<= 1) {
                v0r = fmaxf(v0r, __shfl_xor(v0r, off));
                v1r = fmaxf(v1r, __shfl_xor(v1r, off));
                v2r = fmaxf(v2r, __shfl_xor(v2r, off));
                v3r = fmaxf(v3r, __shfl_xor(v3r, off));
            }
            if (tl == 0) {
                const int o  = wave * 8 + j;
                const int pr = mbase + i * 16 + rgrp * 4;
                if (pr + 0 < NP) out[(pr + 0) * 32 + o] = v0r;
                if (pr + 1 < NP) out[(pr + 1) * 32 + o] = v1r;
                if (pr + 2 < NP) out[(pr + 2) * 32 + o] = v2r;
                if (pr + 3 < NP) out[(pr + 3) * 32 + o] = v3r;
            }
        }
    }
}

extern "C" void kernel_launch(void* const* d_in, const int* in_sizes, int n_in,
                              void* d_out, int out_size, void* d_ws, size_t ws_size,
                              hipStream_t stream) {
    const float* x    = (const float*)d_in[0];
    const int*   cidx = (const int*)d_in[1];
    const float* cval = (const float*)d_in[2];
    const float* w    = (const float*)d_in[3];
    float* out = (float*)d_out;

    __bf16* pw = (__bf16*)d_ws;                               // 1.31 MB

    hipLaunchKernelGGL(prep_weights, dim3(2560), dim3(256), 0, stream, w, pw);
    hipLaunchKernelGGL(fused_gemm_max, dim3(MTILES), dim3(256), 0, stream,
                       x, cidx, cval, (const __bf16*)pw, out);
}

// Round 8
// 188.103 us; speedup vs baseline: 1.1578x; 1.1578x over previous
//
#include <hip/hip_runtime.h>
#include <hip/hip_bf16.h>
#include <stdint.h>

#define NP 30000
#define BBINS 80
#define INCH 16
#define OUTCH 32
#define KDIM 1280       // BBINS*INCH
#define NDIM 512        // OUTCH*TBINS
#define KSTEPS 40       // KDIM/32  (BK=32 = 2 bins)
#define MTILES 469      // ceil(NP/64)

typedef __bf16 bf16x8 __attribute__((ext_vector_type(8)));
typedef float f32x4 __attribute__((ext_vector_type(4)));

__device__ __forceinline__ void async_ld16(const void* g, void* l) {
    __builtin_amdgcn_global_load_lds(
        (const __attribute__((address_space(1))) unsigned int*)g,
        (__attribute__((address_space(3))) unsigned int*)l,
        16, 0, 0);
}

// ---------------------------------------------------------------------------
// Prep: PW[kc][n][qs][e] bf16 with chunk-XOR swizzle qs ^ ((n>>1)&3), where
// lw[k][n] = W[(b+5t)%80][c][o], k=b*16+c, n=o*16+t. (unchanged, proven)
// ---------------------------------------------------------------------------
__global__ void prep_weights(const float* __restrict__ w, __bf16* __restrict__ pw) {
    int gid = blockIdx.x * 256 + threadIdx.x;           // 655360 total
    int e  = gid & 7;
    int qs = (gid >> 3) & 3;
    int n  = (gid >> 5) & 511;
    int kc = gid >> 14;                                  // 0..39
    int kp = kc * 32 + ((qs ^ ((n >> 1) & 3)) << 3) + e; // 0..1279
    int b = kp >> 4, c = kp & 15;
    int o = n >> 4,  t = n & 15;
    int bid = (b + 5 * t) % BBINS;
    pw[gid] = (__bf16)w[(bid * INCH + c) * OUTCH + o];
}

// ---------------------------------------------------------------------------
// FUSED gather + GEMM + max-over-t, software-pipelined gather (T14).
// R7 post-mortem: R7 = pipeline + NONTEMPORAL meta, and the NT half was the
// regression: each meta word is read by TWO threads (half=0/1); NT turned
// the second read from an L2 hit into a second HBM fetch (FETCH 50->124MB)
// and meta prefetch latency from ~200cy(L2) to ~900cy(HBM). This round is
// R7 with plain cached meta loads -- the clean A/B of the pipeline vs R6.
//
// Pipeline per k-step kc:
//   [issue 8 async B(kc)] [hv = pure VALU on preloaded x(kc); ds_write]
//   [issue x(kc+1) loads via preloaded meta(kc+1)] [issue meta(kc+2)]
//   [sync] [ds_read + 32 MFMA] [sync]
// x(kc+1)/meta(kc+2) get ~2 k-steps of slack; the in-step critical chain
// is only VALU + ds_write + B-drain + MFMA.
// Proven invariants kept verbatim: B via global_load_lds from pre-swizzled
// pw; A ds_write chunk-XOR swizzle == q^((row>>1)&3) read swizzle (0
// conflicts measured R6/R7); 4x8 acc wave tile; shfl-max epilogue.
// ---------------------------------------------------------------------------
__global__ __launch_bounds__(256, 2) void fused_gemm_max(
    const float* __restrict__ x,
    const int*   __restrict__ cidx,
    const float* __restrict__ cval,
    const __bf16* __restrict__ pw,
    float* __restrict__ out) {

    __shared__ __align__(16) __bf16 Alds[64 * 32];       // 4 KB
    __shared__ __align__(16) __bf16 Blds[512 * 32];      // 32 KB

    const int mbase = blockIdx.x * 64;
    const int tid  = threadIdx.x;
    const int lane = tid & 63;
    const int wave = tid >> 6;           // n-col group 0..3

    // ---- gather unit mapping ----
    const int patch_l = tid >> 2;        // 0..63
    const int chunk   = tid & 3;         // k-chunk within 64B row
    const int bin_l   = chunk >> 1;      // 0..1
    const int half    = chunk & 1;       // 8-ch half
    int p = mbase + patch_l;
    if (p > NP - 1) p = NP - 1;          // clamp tail (out-write guarded)
    const int row0 = p * BBINS + bin_l;  // conn row; +2 per kstep
    char* aW = (char*)Alds + patch_l * 64
             + ((chunk ^ ((patch_l >> 1) & 3)) << 4);   // swizzled write slot

    // ---- MFMA read offsets (proven swizzle) ----
    const int ml = lane & 15, q = lane >> 4;
    const int f = (ml >> 1) & 3;
    int a_off[4], b_off[8];
#pragma unroll
    for (int i = 0; i < 4; ++i)
        a_off[i] = (i * 16 + ml) * 64 + ((q ^ f) << 4);
#pragma unroll
    for (int j = 0; j < 8; ++j) {
        int nl = wave * 128 + j * 16 + ml;
        b_off[j] = nl * 64 + ((q ^ f) << 4);
    }

    f32x4 acc[4][8];
#pragma unroll
    for (int i = 0; i < 4; ++i)
#pragma unroll
        for (int j = 0; j < 8; ++j)
            acc[i][j] = (f32x4){0.f, 0.f, 0.f, 0.f};

    const char* pwB = (const char*)pw + tid * 16;
    char* bDst = (char*)Blds + tid * 16;

    // ---- gather pipeline prologue ----
    // meta(0) -> va/ia; x(0) -> xa; meta(1) -> vb/ib
    int r3 = row0 * 3;
    int   ia0 = cidx[r3], ia1 = cidx[r3 + 1], ia2 = cidx[r3 + 2];
    float va0 = cval[r3], va1 = cval[r3 + 1], va2 = cval[r3 + 2];
    const float* xp;
    xp = x + (size_t)(unsigned)ia0 * 16 + half * 8;
    float4 xa0 = *(const float4*)xp, xa1 = *(const float4*)(xp + 4);
    xp = x + (size_t)(unsigned)ia1 * 16 + half * 8;
    float4 xa2 = *(const float4*)xp, xa3 = *(const float4*)(xp + 4);
    xp = x + (size_t)(unsigned)ia2 * 16 + half * 8;
    float4 xa4 = *(const float4*)xp, xa5 = *(const float4*)(xp + 4);
    r3 = (row0 + 2) * 3;
    int   ib0 = cidx[r3], ib1 = cidx[r3 + 1], ib2 = cidx[r3 + 2];
    float vb0 = cval[r3], vb1 = cval[r3 + 1], vb2 = cval[r3 + 2];

    for (int kc = 0; kc < KSTEPS; ++kc) {
        // B: 32KB k-chunk, 8 x async 4KB (linear dest, swizzle baked in pw)
        const char* bs = pwB + kc * 32768;
#pragma unroll
        for (int i = 0; i < 8; ++i)
            async_ld16(bs + i * 4096, bDst + i * 4096);

        // A: pure-VALU combine of preloaded x(kc), then ds_write
        bf16x8 hv;
        hv[0] = (__bf16)(va0 * xa0.x + va1 * xa2.x + va2 * xa4.x);
        hv[1] = (__bf16)(va0 * xa0.y + va1 * xa2.y + va2 * xa4.y);
        hv[2] = (__bf16)(va0 * xa0.z + va1 * xa2.z + va2 * xa4.z);
        hv[3] = (__bf16)(va0 * xa0.w + va1 * xa2.w + va2 * xa4.w);
        hv[4] = (__bf16)(va0 * xa1.x + va1 * xa3.x + va2 * xa5.x);
        hv[5] = (__bf16)(va0 * xa1.y + va1 * xa3.y + va2 * xa5.y);
        hv[6] = (__bf16)(va0 * xa1.z + va1 * xa3.z + va2 * xa5.z);
        hv[7] = (__bf16)(va0 * xa1.w + va1 * xa3.w + va2 * xa5.w);
        *(bf16x8*)aW = hv;                               // ds_write_b128

        // prefetch x(kc+1) via meta(kc+1); latency hides under 2 barriers
        float4 nx0 = xa0, nx1 = xa1, nx2 = xa2, nx3 = xa3, nx4 = xa4, nx5 = xa5;
        if (kc + 1 < KSTEPS) {
            xp = x + (size_t)(unsigned)ib0 * 16 + half * 8;
            nx0 = *(const float4*)xp; nx1 = *(const float4*)(xp + 4);
            xp = x + (size_t)(unsigned)ib1 * 16 + half * 8;
            nx2 = *(const float4*)xp; nx3 = *(const float4*)(xp + 4);
            xp = x + (size_t)(unsigned)ib2 * 16 + half * 8;
            nx4 = *(const float4*)xp; nx5 = *(const float4*)(xp + 4);
        }
        // prefetch meta(kc+2) -- PLAIN cached loads (R7's NT here was the
        // regression: meta is read by 2 threads; NT doubled its HBM traffic)
        int   ni0 = ib0, ni1 = ib1, ni2 = ib2;
        float nv0 = vb0, nv1 = vb1, nv2 = vb2;
        if (kc + 2 < KSTEPS) {
            r3 = (row0 + (kc + 2) * 2) * 3;
            ni0 = cidx[r3 + 0]; ni1 = cidx[r3 + 1]; ni2 = cidx[r3 + 2];
            nv0 = cval[r3 + 0]; nv1 = cval[r3 + 1]; nv2 = cval[r3 + 2];
        }
        __syncthreads();                                 // drains vm+lgkm

        bf16x8 af[4], bfr[8];
#pragma unroll
        for (int i = 0; i < 4; ++i)
            af[i] = *(const bf16x8*)((const char*)Alds + a_off[i]);
#pragma unroll
        for (int j = 0; j < 8; ++j)
            bfr[j] = *(const bf16x8*)((const char*)Blds + b_off[j]);
#pragma unroll
        for (int i = 0; i < 4; ++i)
#pragma unroll
            for (int j = 0; j < 8; ++j)
                acc[i][j] = __builtin_amdgcn_mfma_f32_16x16x32_bf16(
                    af[i], bfr[j], acc[i][j], 0, 0, 0);
        __syncthreads();

        // rotate pipeline registers
        va0 = vb0; va1 = vb1; va2 = vb2;
        xa0 = nx0; xa1 = nx1; xa2 = nx2; xa3 = nx3; xa4 = nx4; xa5 = nx5;
        ib0 = ni0; ib1 = ni1; ib2 = ni2;
        vb0 = nv0; vb1 = nv1; vb2 = nv2;
    }

    const int rgrp = lane >> 4;
    const int tl   = lane & 15;
#pragma unroll
    for (int i = 0; i < 4; ++i) {
#pragma unroll
        for (int j = 0; j < 8; ++j) {
            float v0r = acc[i][j][0], v1r = acc[i][j][1];
            float v2r = acc[i][j][2], v3r = acc[i][j][3];
#pragma unroll
            for (int off = 1; off < 16; off <<= 1) {
                v0r = fmaxf(v0r, __shfl_xor(v0r, off));
                v1r = fmaxf(v1r, __shfl_xor(v1r, off));
                v2r = fmaxf(v2r, __shfl_xor(v2r, off));
                v3r = fmaxf(v3r, __shfl_xor(v3r, off));
            }
            if (tl == 0) {
                const int o  = wave * 8 + j;
                const int pr = mbase + i * 16 + rgrp * 4;
                if (pr + 0 < NP) out[(pr + 0) * 32 + o] = v0r;
                if (pr + 1 < NP) out[(pr + 1) * 32 + o] = v1r;
                if (pr + 2 < NP) out[(pr + 2) * 32 + o] = v2r;
                if (pr + 3 < NP) out[(pr + 3) * 32 + o] = v3r;
            }
        }
    }
}

extern "C" void kernel_launch(void* const* d_in, const int* in_sizes, int n_in,
                              void* d_out, int out_size, void* d_ws, size_t ws_size,
                              hipStream_t stream) {
    const float* x    = (const float*)d_in[0];
    const int*   cidx = (const int*)d_in[1];
    const float* cval = (const float*)d_in[2];
    const float* w    = (const float*)d_in[3];
    float* out = (float*)d_out;

    __bf16* pw = (__bf16*)d_ws;                               // 1.31 MB

    hipLaunchKernelGGL(prep_weights, dim3(2560), dim3(256), 0, stream, w, pw);
    hipLaunchKernelGGL(fused_gemm_max, dim3(MTILES), dim3(256), 0, stream,
                       x, cidx, cval, (const __bf16*)pw, out);
}